// Round 13
// baseline (119.660 us; speedup 1.0000x reference)
//
#include <hip/hip_runtime.h>
#include <math.h>

#define NDIM 128
#define CAP 64     // per-node slot capacity; deg ~ Poisson(16), max ~40 << 64
#define BCAP 4096  // per-bucket edge capacity; avg 2046, max ~2350 << 4096

typedef _Float16 half2v __attribute__((ext_vector_type(2)));
typedef _Float16 half4v __attribute__((ext_vector_type(4)));
typedef _Float16 half8v __attribute__((ext_vector_type(8)));
typedef __attribute__((ext_vector_type(4))) float f32x4;

__device__ inline float fdot2h(half2v a, half2v b, float c) {
#if __has_builtin(__builtin_amdgcn_fdot2)
  return __builtin_amdgcn_fdot2(a, b, c, false);
#else
  return fmaf((float)a.x, (float)b.x, fmaf((float)a.y, (float)b.y, c));
#endif
}

__device__ inline half2v h2cast(unsigned u) { return __builtin_bit_cast(half2v, u); }

// ---------------- prep: W -> f16 FRAGMENT-MAJOR + zero bucket cursors --------
__global__ __launch_bounds__(256) void prep_kernel(
    const float* __restrict__ Wq, const float* __restrict__ Wk,
    const float* __restrict__ Wv, _Float16* __restrict__ wtf,
    int* __restrict__ gcur, int nbuck) {
  int tid = blockIdx.x * 256 + threadIdx.x;
  if (tid < 3 * NDIM * NDIM) {
    int mat = tid >> 14;
    int rem = tid & 16383;
    int mtg = rem >> 11;
    int kk = (rem >> 9) & 3;
    int lane = (rem >> 3) & 63;
    int j = rem & 7;
    int m = mtg * 16 + (lane & 15);
    int kx = kk * 32 + (lane >> 4) * 8 + j;
    const float* W = (mat == 0) ? Wq : (mat == 1) ? Wk : Wv;
    wtf[tid] = (_Float16)W[kx * NDIM + m];
  }
  int nthr = gridDim.x * 256;
  int tot = nbuck * 16;
  for (int i = tid; i < tot; i += nthr) gcur[i] = 0;
}

// ------------- fused heterogeneous kernel: partitionA-blocks + qkv-blocks ----
// blockIdx < nscat: coarse radix partition by dst>>7; pairs stored COMPRESSED
//   as u32 = src<<7 | (dst&127)  (src < 50000 < 2^16).
// blockIdx >= nscat: f16 MFMA projections; k,v written INTERLEAVED in kvh.
__global__ __launch_bounds__(512) void fused_kernel(
    const float* __restrict__ z, const _Float16* __restrict__ wtf,
    const float* __restrict__ bq, const float* __restrict__ bk,
    const float* __restrict__ bv,
    _Float16* __restrict__ qh, _Float16* __restrict__ kvh,
    int n,
    const int* __restrict__ src, const int* __restrict__ dst,
    int* __restrict__ gcur, unsigned* __restrict__ part, int ne, int nbuck,
    int nscat) {
  __shared__ int lhist[512];
  __shared__ int lbase[512];
  __shared__ int lcur[512];
  if ((int)blockIdx.x < nscat) {
    // ---- partition-A role: 4 edges per thread, two LDS passes ----
    int tid = threadIdx.x;
    for (int i = tid; i < nbuck; i += 512) lhist[i] = 0;
    __syncthreads();
    int e0 = (blockIdx.x * 512 + tid) * 4;
    int dd0 = 0, dd1 = 0, dd2 = 0, dd3 = 0, ss0 = 0, ss1 = 0, ss2 = 0, ss3 = 0;
    bool v0 = false, v1 = false, v2 = false, v3 = false;
    if (e0 + 3 < ne) {
      int4 d = *(const int4*)(dst + e0);
      int4 s = *(const int4*)(src + e0);
      dd0 = d.x; dd1 = d.y; dd2 = d.z; dd3 = d.w;
      ss0 = s.x; ss1 = s.y; ss2 = s.z; ss3 = s.w;
      v0 = v1 = v2 = v3 = true;
    } else {
      if (e0 + 0 < ne) { dd0 = dst[e0 + 0]; ss0 = src[e0 + 0]; v0 = true; }
      if (e0 + 1 < ne) { dd1 = dst[e0 + 1]; ss1 = src[e0 + 1]; v1 = true; }
      if (e0 + 2 < ne) { dd2 = dst[e0 + 2]; ss2 = src[e0 + 2]; v2 = true; }
      if (e0 + 3 < ne) { dd3 = dst[e0 + 3]; ss3 = src[e0 + 3]; v3 = true; }
    }
    if (v0) atomicAdd(&lhist[dd0 >> 7], 1);
    if (v1) atomicAdd(&lhist[dd1 >> 7], 1);
    if (v2) atomicAdd(&lhist[dd2 >> 7], 1);
    if (v3) atomicAdd(&lhist[dd3 >> 7], 1);
    __syncthreads();
    if (tid < nbuck) {
      int c = lhist[tid];
      lbase[tid] = (c > 0) ? atomicAdd(&gcur[tid * 16], c) : 0;
      lcur[tid] = 0;
    }
    __syncthreads();
    if (v0) { int b = dd0 >> 7; int p = lbase[b] + atomicAdd(&lcur[b], 1);
              if (p < BCAP) part[(size_t)b * BCAP + p] =
                  ((unsigned)ss0 << 7) | (unsigned)(dd0 & 127); }
    if (v1) { int b = dd1 >> 7; int p = lbase[b] + atomicAdd(&lcur[b], 1);
              if (p < BCAP) part[(size_t)b * BCAP + p] =
                  ((unsigned)ss1 << 7) | (unsigned)(dd1 & 127); }
    if (v2) { int b = dd2 >> 7; int p = lbase[b] + atomicAdd(&lcur[b], 1);
              if (p < BCAP) part[(size_t)b * BCAP + p] =
                  ((unsigned)ss2 << 7) | (unsigned)(dd2 & 127); }
    if (v3) { int b = dd3 >> 7; int p = lbase[b] + atomicAdd(&lcur[b], 1);
              if (p < BCAP) part[(size_t)b * BCAP + p] =
                  ((unsigned)ss3 << 7) | (unsigned)(dd3 & 127); }
    return;
  }
  // ---- qkv role: 8 waves; wave = 16 rows x 64 cols ----
  int bid = blockIdx.x - nscat;
  int lane = threadIdx.x & 63;
  int w = threadIdx.x >> 6;
  int rowgrp = w >> 1, colhalf = w & 1;
  int l15 = lane & 15, kgrp = lane >> 4;
  int row_b = bid * 64 + rowgrp * 16 + l15;
  bool ok = row_b < n;
  const float* zrow = z + (size_t)row_b * NDIM;
  half8v bfr[4];
#pragma unroll
  for (int kk = 0; kk < 4; ++kk) {
    half8v bv8 = (half8v)0;
    if (ok) {
      const float4* zp = (const float4*)(zrow + kk * 32 + kgrp * 8);
      float4 a0 = zp[0], a1 = zp[1];
      bv8[0] = (_Float16)a0.x; bv8[1] = (_Float16)a0.y;
      bv8[2] = (_Float16)a0.z; bv8[3] = (_Float16)a0.w;
      bv8[4] = (_Float16)a1.x; bv8[5] = (_Float16)a1.y;
      bv8[6] = (_Float16)a1.z; bv8[7] = (_Float16)a1.w;
    }
    bfr[kk] = bv8;
  }
#pragma unroll
  for (int mat = 0; mat < 3; ++mat) {
    const _Float16* wf = wtf + (size_t)mat * NDIM * NDIM;
    const float* bias = (mat == 0) ? bq : (mat == 1) ? bk : bv;
    _Float16* outp = (mat == 0) ? qh : kvh;
    int rstride = (mat == 0) ? NDIM : 2 * NDIM;
    int coff = (mat == 2) ? NDIM : 0;
    f32x4 acc[4];
#pragma unroll
    for (int mt = 0; mt < 4; ++mt) acc[mt] = (f32x4)0.f;
#pragma unroll
    for (int mt = 0; mt < 4; ++mt) {
      int mtg = colhalf * 4 + mt;
#pragma unroll
      for (int kk = 0; kk < 4; ++kk) {
        half8v afr = *(const half8v*)(wf + (((mtg * 4 + kk) * 64) + lane) * 8);
        acc[mt] = __builtin_amdgcn_mfma_f32_16x16x32_f16(afr, bfr[kk], acc[mt],
                                                         0, 0, 0);
      }
    }
    if (ok) {
#pragma unroll
      for (int mt = 0; mt < 4; ++mt) {
        int c0 = colhalf * 64 + mt * 16 + kgrp * 4;
        float4 bb = *(const float4*)(bias + c0);
        half4v pk;
        pk[0] = (_Float16)(acc[mt][0] + bb.x);
        pk[1] = (_Float16)(acc[mt][1] + bb.y);
        pk[2] = (_Float16)(acc[mt][2] + bb.z);
        pk[3] = (_Float16)(acc[mt][3] + bb.w);
        *(half4v*)(outp + (size_t)row_b * rstride + coff + c0) = pk;
      }
    }
  }
}

// ---------------- mega-agg: per-bucket LDS rank + softmax-aggregate ----------
// Block = bucket of 128 nodes, 1024 threads (16 waves). Phase 1: rank the
// bucket's u32 pairs into LDS u16 slot lists. Phase 2: per wave, 8 nodes with
// the 4-group pipeline, SOFTWARE-PIPELINED k/v gathers (issue s+1 before
// consuming s) to keep loads continuously in flight.
__global__ __launch_bounds__(1024) void megaagg_kernel(
    const _Float16* __restrict__ qh, const _Float16* __restrict__ kvh,
    const unsigned* __restrict__ part, const int* __restrict__ gcur,
    float* __restrict__ out, int n) {
  __shared__ unsigned short lslots[128 * CAP];  // 16 KB
  __shared__ int lcur[128];
  int tid = threadIdx.x;
  int nb = blockIdx.x;
  if (tid < 128) lcur[tid] = 0;
  __syncthreads();
  int cnt = gcur[nb * 16];
  if (cnt > BCAP) cnt = BCAP;
  const unsigned* pp = part + (size_t)nb * BCAP;
  for (int i = tid; i < cnt; i += 1024) {
    unsigned p = pp[i];
    int nl = (int)(p & 127u);
    int r = atomicAdd(&lcur[nl], 1);
    if (r < CAP) lslots[(nl << 6) + r] = (unsigned short)(p >> 7);
  }
  __syncthreads();
  const float tau = 0.08838834764831845f;  // 1/sqrt(128)
  const float M0 = 8.0f;                   // static max guard
  int wv = tid >> 6;
  int lane = tid & 63;
  int gl = lane & 15;   // lane in group: dims [gl*8, gl*8+8)
  int grp = lane >> 4;  // group 0..3
#pragma unroll
  for (int t = 0; t < 8; ++t) {
    int nl = wv * 8 + t;
    int node = nb * 128 + nl;
    if (node >= n) break;  // wave-uniform
    int cnt2 = lcur[nl];
    if (cnt2 > CAP) cnt2 = CAP;
    uint4 qv = *(const uint4*)(qh + (size_t)node * NDIM + gl * 8);
    half2v q0 = h2cast(qv.x), q1 = h2cast(qv.y);
    half2v q2 = h2cast(qv.z), q3 = h2cast(qv.w);
    float se = 0.f;
    float h[8];
#pragma unroll
    for (int i = 0; i < 8; ++i) h[i] = 0.f;
    int sj = (lane < cnt2) ? (int)lslots[(nl << 6) + lane] : 0;
    int nsub = (cnt2 + 3) >> 2;
    // software pipeline: issue s+1's loads before consuming s's
    uint4 kv, vv;
    bool en = grp < cnt2;
    {
      int row = __shfl(sj, grp);
      if (en) {
        const _Float16* kvrow = kvh + (size_t)row * 2 * NDIM;
        kv = *(const uint4*)(kvrow + gl * 8);
        vv = *(const uint4*)(kvrow + NDIM + gl * 8);
      }
    }
    for (int s = 0; s < nsub; ++s) {
      uint4 kvn, vvn;
      int jn = ((s + 1) << 2) | grp;
      bool enn = jn < cnt2;
      int rown = __shfl(sj, jn & 63);
      if (enn) {  // issue next edge's gathers NOW (consumed next iter)
        const _Float16* kvrow = kvh + (size_t)rown * 2 * NDIM;
        kvn = *(const uint4*)(kvrow + gl * 8);
        vvn = *(const uint4*)(kvrow + NDIM + gl * 8);
      }
      if (en) {
        float p = fdot2h(h2cast(kv.x), q0, 0.f);
        p = fdot2h(h2cast(kv.y), q1, p);
        p = fdot2h(h2cast(kv.z), q2, p);
        p = fdot2h(h2cast(kv.w), q3, p);
        p += __shfl_xor(p, 1);
        p += __shfl_xor(p, 2);
        p += __shfl_xor(p, 4);
        p += __shfl_xor(p, 8);
        float ex = __expf(fmaf(p, tau, -M0));
        se += ex;
        half2v v0 = h2cast(vv.x), v1 = h2cast(vv.y);
        half2v v2 = h2cast(vv.z), v3 = h2cast(vv.w);
        h[0] = fmaf(ex, (float)v0.x, h[0]);
        h[1] = fmaf(ex, (float)v0.y, h[1]);
        h[2] = fmaf(ex, (float)v1.x, h[2]);
        h[3] = fmaf(ex, (float)v1.y, h[3]);
        h[4] = fmaf(ex, (float)v2.x, h[4]);
        h[5] = fmaf(ex, (float)v2.y, h[5]);
        h[6] = fmaf(ex, (float)v3.x, h[6]);
        h[7] = fmaf(ex, (float)v3.y, h[7]);
      }
      kv = kvn;
      vv = vvn;
      en = enn;
    }
    // cross-group reduce (se uniform within group; h partial per group)
    se += __shfl_xor(se, 16);
    se += __shfl_xor(se, 32);
#pragma unroll
    for (int i = 0; i < 8; ++i) {
      h[i] += __shfl_xor(h[i], 16);
      h[i] += __shfl_xor(h[i], 32);
    }
    if (grp == 0) {
      float inv = 1.f / ((se > 0.f) ? se : 1.f);
      float4* op = (float4*)(out + (size_t)node * NDIM + gl * 8);
      op[0] = make_float4(h[0] * inv, h[1] * inv, h[2] * inv, h[3] * inv);
      op[1] = make_float4(h[4] * inv, h[5] * inv, h[6] * inv, h[7] * inv);
    }
  }
}

extern "C" void kernel_launch(void* const* d_in, const int* in_sizes, int n_in,
                              void* d_out, int out_size, void* d_ws, size_t ws_size,
                              hipStream_t stream) {
  const float* z  = (const float*)d_in[0];
  const float* Wq = (const float*)d_in[1];
  const float* bq = (const float*)d_in[2];
  const float* Wk = (const float*)d_in[3];
  const float* bk = (const float*)d_in[4];
  const float* Wv = (const float*)d_in[5];
  const float* bv = (const float*)d_in[6];
  const int* src  = (const int*)d_in[7];
  const int* dst  = (const int*)d_in[8];
  int n  = in_sizes[0] / NDIM;  // 50000
  int ne = in_sizes[7];         // 800000
  float* out = (float*)d_out;

  int nbuck = (n + 127) >> 7;  // 391 buckets of 128 nodes (dst>>7); <=512

  char* ws = (char*)d_ws;
  size_t szh = (size_t)n * NDIM * sizeof(_Float16);  // 12.8 MB
  size_t off = 0;
  _Float16* qh  = (_Float16*)(ws + off); off += szh;
  _Float16* kvh = (_Float16*)(ws + off); off += 2 * szh;  // interleaved k|v
  _Float16* wtf = (_Float16*)(ws + off);
  off += ((size_t)3 * NDIM * NDIM * sizeof(_Float16) + 255) & ~(size_t)255;
  int* gcur = (int*)(ws + off);
  off += (((size_t)nbuck * 16 * sizeof(int)) + 255) & ~(size_t)255;  // 25 KB
  unsigned* part = (unsigned*)(ws + off);
  off += (size_t)nbuck * BCAP * sizeof(unsigned);                    // 6.4 MB

  int nscat = (ne / 4 + 511) / 512;  // 391 partition-A blocks
  int nqkv  = (n + 63) / 64;         // 782 qkv blocks

  // 1) W -> f16 fragment-major, zero bucket cursors
  prep_kernel<<<256, 256, 0, stream>>>(Wq, Wk, Wv, wtf, gcur, nbuck);
  // 2) fused: partition-A blocks (first) + qkv-MFMA-blocks (kv interleaved)
  fused_kernel<<<nscat + nqkv, 512, 0, stream>>>(z, wtf, bq, bk, bv, qh, kvh, n,
                                                 src, dst, gcur, part, ne, nbuck,
                                                 nscat);
  // 3) mega-agg: per-bucket LDS rank + pipelined softmax-aggregate
  megaagg_kernel<<<nbuck, 1024, 0, stream>>>(qh, kvh, part, gcur, out, n);
}

// Round 14
// 118.083 us; speedup vs baseline: 1.0134x; 1.0134x over previous
//
#include <hip/hip_runtime.h>
#include <math.h>

#define NDIM 128
#define CAP 64     // per-node slot capacity; deg ~ Poisson(16), max ~40 << 64
#define BCAP 4096  // per-bucket edge capacity; avg 2046, max ~2350 << 4096

typedef _Float16 half2v __attribute__((ext_vector_type(2)));
typedef _Float16 half4v __attribute__((ext_vector_type(4)));
typedef _Float16 half8v __attribute__((ext_vector_type(8)));
typedef __attribute__((ext_vector_type(4))) float f32x4;

__device__ inline float fdot2h(half2v a, half2v b, float c) {
#if __has_builtin(__builtin_amdgcn_fdot2)
  return __builtin_amdgcn_fdot2(a, b, c, false);
#else
  return fmaf((float)a.x, (float)b.x, fmaf((float)a.y, (float)b.y, c));
#endif
}

__device__ inline half2v h2cast(unsigned u) { return __builtin_bit_cast(half2v, u); }

// ---------------- prep: W -> f16 FRAGMENT-MAJOR + zero bucket cursors --------
__global__ __launch_bounds__(256) void prep_kernel(
    const float* __restrict__ Wq, const float* __restrict__ Wk,
    const float* __restrict__ Wv, _Float16* __restrict__ wtf,
    int* __restrict__ gcur, int nbuck) {
  int tid = blockIdx.x * 256 + threadIdx.x;
  if (tid < 3 * NDIM * NDIM) {
    int mat = tid >> 14;
    int rem = tid & 16383;
    int mtg = rem >> 11;
    int kk = (rem >> 9) & 3;
    int lane = (rem >> 3) & 63;
    int j = rem & 7;
    int m = mtg * 16 + (lane & 15);
    int kx = kk * 32 + (lane >> 4) * 8 + j;
    const float* W = (mat == 0) ? Wq : (mat == 1) ? Wk : Wv;
    wtf[tid] = (_Float16)W[kx * NDIM + m];
  }
  int nthr = gridDim.x * 256;
  int tot = nbuck * 16;
  for (int i = tid; i < tot; i += nthr) gcur[i] = 0;
}

// ------------- fused heterogeneous kernel: partitionA-blocks + qkv-blocks ----
// blockIdx < nscat: coarse radix partition by dst>>7; pairs stored COMPRESSED
//   as u32 = src<<7 | (dst&127)  (src < 50000 < 2^16).
// blockIdx >= nscat: f16 MFMA projections; wave = 16 rows x FULL 128 cols
//   (z rows loaded once per wave, no colhalf duplication); k,v interleaved.
__global__ __launch_bounds__(512) void fused_kernel(
    const float* __restrict__ z, const _Float16* __restrict__ wtf,
    const float* __restrict__ bq, const float* __restrict__ bk,
    const float* __restrict__ bv,
    _Float16* __restrict__ qh, _Float16* __restrict__ kvh,
    int n,
    const int* __restrict__ src, const int* __restrict__ dst,
    int* __restrict__ gcur, unsigned* __restrict__ part, int ne, int nbuck,
    int nscat) {
  __shared__ int lhist[512];
  __shared__ int lbase[512];
  __shared__ int lcur[512];
  if ((int)blockIdx.x < nscat) {
    // ---- partition-A role: 4 edges per thread, two LDS passes ----
    int tid = threadIdx.x;
    for (int i = tid; i < nbuck; i += 512) lhist[i] = 0;
    __syncthreads();
    int e0 = (blockIdx.x * 512 + tid) * 4;
    int dd0 = 0, dd1 = 0, dd2 = 0, dd3 = 0, ss0 = 0, ss1 = 0, ss2 = 0, ss3 = 0;
    bool v0 = false, v1 = false, v2 = false, v3 = false;
    if (e0 + 3 < ne) {
      int4 d = *(const int4*)(dst + e0);
      int4 s = *(const int4*)(src + e0);
      dd0 = d.x; dd1 = d.y; dd2 = d.z; dd3 = d.w;
      ss0 = s.x; ss1 = s.y; ss2 = s.z; ss3 = s.w;
      v0 = v1 = v2 = v3 = true;
    } else {
      if (e0 + 0 < ne) { dd0 = dst[e0 + 0]; ss0 = src[e0 + 0]; v0 = true; }
      if (e0 + 1 < ne) { dd1 = dst[e0 + 1]; ss1 = src[e0 + 1]; v1 = true; }
      if (e0 + 2 < ne) { dd2 = dst[e0 + 2]; ss2 = src[e0 + 2]; v2 = true; }
      if (e0 + 3 < ne) { dd3 = dst[e0 + 3]; ss3 = src[e0 + 3]; v3 = true; }
    }
    if (v0) atomicAdd(&lhist[dd0 >> 7], 1);
    if (v1) atomicAdd(&lhist[dd1 >> 7], 1);
    if (v2) atomicAdd(&lhist[dd2 >> 7], 1);
    if (v3) atomicAdd(&lhist[dd3 >> 7], 1);
    __syncthreads();
    if (tid < nbuck) {
      int c = lhist[tid];
      lbase[tid] = (c > 0) ? atomicAdd(&gcur[tid * 16], c) : 0;
      lcur[tid] = 0;
    }
    __syncthreads();
    if (v0) { int b = dd0 >> 7; int p = lbase[b] + atomicAdd(&lcur[b], 1);
              if (p < BCAP) part[(size_t)b * BCAP + p] =
                  ((unsigned)ss0 << 7) | (unsigned)(dd0 & 127); }
    if (v1) { int b = dd1 >> 7; int p = lbase[b] + atomicAdd(&lcur[b], 1);
              if (p < BCAP) part[(size_t)b * BCAP + p] =
                  ((unsigned)ss1 << 7) | (unsigned)(dd1 & 127); }
    if (v2) { int b = dd2 >> 7; int p = lbase[b] + atomicAdd(&lcur[b], 1);
              if (p < BCAP) part[(size_t)b * BCAP + p] =
                  ((unsigned)ss2 << 7) | (unsigned)(dd2 & 127); }
    if (v3) { int b = dd3 >> 7; int p = lbase[b] + atomicAdd(&lcur[b], 1);
              if (p < BCAP) part[(size_t)b * BCAP + p] =
                  ((unsigned)ss3 << 7) | (unsigned)(dd3 & 127); }
    return;
  }
  // ---- qkv role: 8 waves; wave = 16 rows x 128 cols (no duplication) ----
  int bid = blockIdx.x - nscat;
  int lane = threadIdx.x & 63;
  int w = threadIdx.x >> 6;
  int l15 = lane & 15, kgrp = lane >> 4;
  int row_b = bid * 128 + w * 16 + l15;
  bool ok = row_b < n;
  const float* zrow = z + (size_t)row_b * NDIM;
  half8v bfr[4];
#pragma unroll
  for (int kk = 0; kk < 4; ++kk) {
    half8v bv8 = (half8v)0;
    if (ok) {
      const float4* zp = (const float4*)(zrow + kk * 32 + kgrp * 8);
      float4 a0 = zp[0], a1 = zp[1];
      bv8[0] = (_Float16)a0.x; bv8[1] = (_Float16)a0.y;
      bv8[2] = (_Float16)a0.z; bv8[3] = (_Float16)a0.w;
      bv8[4] = (_Float16)a1.x; bv8[5] = (_Float16)a1.y;
      bv8[6] = (_Float16)a1.z; bv8[7] = (_Float16)a1.w;
    }
    bfr[kk] = bv8;
  }
#pragma unroll
  for (int mat = 0; mat < 3; ++mat) {
    const _Float16* wf = wtf + (size_t)mat * NDIM * NDIM;
    const float* bias = (mat == 0) ? bq : (mat == 1) ? bk : bv;
    _Float16* outp = (mat == 0) ? qh : kvh;
    int rstride = (mat == 0) ? NDIM : 2 * NDIM;
    int coff = (mat == 2) ? NDIM : 0;
    f32x4 acc[8];
#pragma unroll
    for (int mtg = 0; mtg < 8; ++mtg) acc[mtg] = (f32x4)0.f;
#pragma unroll
    for (int mtg = 0; mtg < 8; ++mtg) {
#pragma unroll
      for (int kk = 0; kk < 4; ++kk) {
        half8v afr = *(const half8v*)(wf + (((mtg * 4 + kk) * 64) + lane) * 8);
        acc[mtg] = __builtin_amdgcn_mfma_f32_16x16x32_f16(afr, bfr[kk], acc[mtg],
                                                          0, 0, 0);
      }
    }
    if (ok) {
#pragma unroll
      for (int mtg = 0; mtg < 8; ++mtg) {
        int c0 = mtg * 16 + kgrp * 4;
        float4 bb = *(const float4*)(bias + c0);
        half4v pk;
        pk[0] = (_Float16)(acc[mtg][0] + bb.x);
        pk[1] = (_Float16)(acc[mtg][1] + bb.y);
        pk[2] = (_Float16)(acc[mtg][2] + bb.z);
        pk[3] = (_Float16)(acc[mtg][3] + bb.w);
        *(half4v*)(outp + (size_t)row_b * rstride + coff + c0) = pk;
      }
    }
  }
}

// ---------------- mega-agg: per-bucket LDS rank + softmax-aggregate ----------
// Block = bucket of 128 nodes, 1024 threads (16 waves). Phase 1: rank the
// bucket's u32 pairs into LDS u16 slot lists (LDS atomics only). Phase 2: each
// wave aggregates 8 nodes with the proven 4-group pipeline; k,v gathered from
// the interleaved kvh rows. Static-max softmax (exp(e-8), identical ratio).
__global__ __launch_bounds__(1024) void megaagg_kernel(
    const _Float16* __restrict__ qh, const _Float16* __restrict__ kvh,
    const unsigned* __restrict__ part, const int* __restrict__ gcur,
    float* __restrict__ out, int n) {
  __shared__ unsigned short lslots[128 * CAP];  // 16 KB
  __shared__ int lcur[128];
  int tid = threadIdx.x;
  int nb = blockIdx.x;
  if (tid < 128) lcur[tid] = 0;
  __syncthreads();
  int cnt = gcur[nb * 16];
  if (cnt > BCAP) cnt = BCAP;
  const unsigned* pp = part + (size_t)nb * BCAP;
  for (int i = tid; i < cnt; i += 1024) {
    unsigned p = pp[i];
    int nl = (int)(p & 127u);
    int r = atomicAdd(&lcur[nl], 1);
    if (r < CAP) lslots[(nl << 6) + r] = (unsigned short)(p >> 7);
  }
  __syncthreads();
  const float tau = 0.08838834764831845f;  // 1/sqrt(128)
  const float M0 = 8.0f;                   // static max guard
  int wv = tid >> 6;
  int lane = tid & 63;
  int gl = lane & 15;   // lane in group: dims [gl*8, gl*8+8)
  int grp = lane >> 4;  // group 0..3
#pragma unroll
  for (int t = 0; t < 8; ++t) {
    int nl = wv * 8 + t;
    int node = nb * 128 + nl;
    if (node >= n) break;  // wave-uniform
    int cnt2 = lcur[nl];
    if (cnt2 > CAP) cnt2 = CAP;
    uint4 qv = *(const uint4*)(qh + (size_t)node * NDIM + gl * 8);
    half2v q0 = h2cast(qv.x), q1 = h2cast(qv.y);
    half2v q2 = h2cast(qv.z), q3 = h2cast(qv.w);
    float se = 0.f;
    float h[8];
#pragma unroll
    for (int i = 0; i < 8; ++i) h[i] = 0.f;
    int sj = (lane < cnt2) ? (int)lslots[(nl << 6) + lane] : 0;
    int nsub = (cnt2 + 3) >> 2;
    for (int s = 0; s < nsub; ++s) {
      int j = (s << 2) | grp;
      int row = __shfl(sj, j);
      bool en = j < cnt2;  // uniform within a 16-lane group
      uint4 kv, vv;
      if (en) {  // k and v in ONE 512B row -> locality + 2 loads in flight
        const _Float16* kvrow = kvh + (size_t)row * 2 * NDIM;
        kv = *(const uint4*)(kvrow + gl * 8);
        vv = *(const uint4*)(kvrow + NDIM + gl * 8);
      }
      if (en) {
        float p = fdot2h(h2cast(kv.x), q0, 0.f);
        p = fdot2h(h2cast(kv.y), q1, p);
        p = fdot2h(h2cast(kv.z), q2, p);
        p = fdot2h(h2cast(kv.w), q3, p);
        p += __shfl_xor(p, 1);
        p += __shfl_xor(p, 2);
        p += __shfl_xor(p, 4);
        p += __shfl_xor(p, 8);
        float ex = __expf(fmaf(p, tau, -M0));
        se += ex;
        half2v v0 = h2cast(vv.x), v1 = h2cast(vv.y);
        half2v v2 = h2cast(vv.z), v3 = h2cast(vv.w);
        h[0] = fmaf(ex, (float)v0.x, h[0]);
        h[1] = fmaf(ex, (float)v0.y, h[1]);
        h[2] = fmaf(ex, (float)v1.x, h[2]);
        h[3] = fmaf(ex, (float)v1.y, h[3]);
        h[4] = fmaf(ex, (float)v2.x, h[4]);
        h[5] = fmaf(ex, (float)v2.y, h[5]);
        h[6] = fmaf(ex, (float)v3.x, h[6]);
        h[7] = fmaf(ex, (float)v3.y, h[7]);
      }
    }
    // cross-group reduce (se uniform within group; h partial per group)
    se += __shfl_xor(se, 16);
    se += __shfl_xor(se, 32);
#pragma unroll
    for (int i = 0; i < 8; ++i) {
      h[i] += __shfl_xor(h[i], 16);
      h[i] += __shfl_xor(h[i], 32);
    }
    if (grp == 0) {
      float inv = 1.f / ((se > 0.f) ? se : 1.f);
      float4* op = (float4*)(out + (size_t)node * NDIM + gl * 8);
      op[0] = make_float4(h[0] * inv, h[1] * inv, h[2] * inv, h[3] * inv);
      op[1] = make_float4(h[4] * inv, h[5] * inv, h[6] * inv, h[7] * inv);
    }
  }
}

extern "C" void kernel_launch(void* const* d_in, const int* in_sizes, int n_in,
                              void* d_out, int out_size, void* d_ws, size_t ws_size,
                              hipStream_t stream) {
  const float* z  = (const float*)d_in[0];
  const float* Wq = (const float*)d_in[1];
  const float* bq = (const float*)d_in[2];
  const float* Wk = (const float*)d_in[3];
  const float* bk = (const float*)d_in[4];
  const float* Wv = (const float*)d_in[5];
  const float* bv = (const float*)d_in[6];
  const int* src  = (const int*)d_in[7];
  const int* dst  = (const int*)d_in[8];
  int n  = in_sizes[0] / NDIM;  // 50000
  int ne = in_sizes[7];         // 800000
  float* out = (float*)d_out;

  int nbuck = (n + 127) >> 7;  // 391 buckets of 128 nodes (dst>>7); <=512

  char* ws = (char*)d_ws;
  size_t szh = (size_t)n * NDIM * sizeof(_Float16);  // 12.8 MB
  size_t off = 0;
  _Float16* qh  = (_Float16*)(ws + off); off += szh;
  _Float16* kvh = (_Float16*)(ws + off); off += 2 * szh;  // interleaved k|v
  _Float16* wtf = (_Float16*)(ws + off);
  off += ((size_t)3 * NDIM * NDIM * sizeof(_Float16) + 255) & ~(size_t)255;
  int* gcur = (int*)(ws + off);
  off += (((size_t)nbuck * 16 * sizeof(int)) + 255) & ~(size_t)255;  // 25 KB
  unsigned* part = (unsigned*)(ws + off);
  off += (size_t)nbuck * BCAP * sizeof(unsigned);                    // 6.4 MB

  int nscat = (ne / 4 + 511) / 512;  // 391 partition-A blocks
  int nqkv  = (n + 127) / 128;       // 391 qkv blocks (128 rows each)

  // 1) W -> f16 fragment-major, zero bucket cursors
  prep_kernel<<<256, 256, 0, stream>>>(Wq, Wk, Wv, wtf, gcur, nbuck);
  // 2) fused: partition-A blocks (first) + qkv-MFMA-blocks (kv interleaved)
  fused_kernel<<<nscat + nqkv, 512, 0, stream>>>(z, wtf, bq, bk, bv, qh, kvh, n,
                                                 src, dst, gcur, part, ne, nbuck,
                                                 nscat);
  // 3) mega-agg: per-bucket LDS rank + softmax-aggregate
  megaagg_kernel<<<nbuck, 1024, 0, stream>>>(qh, kvh, part, gcur, out, n);
}

// Round 15
// 116.427 us; speedup vs baseline: 1.0278x; 1.0142x over previous
//
#include <hip/hip_runtime.h>
#include <math.h>

#define NDIM 128
#define CAP 64     // per-node slot capacity; deg ~ Poisson(16), max ~40 << 64
#define BCAP 2048  // per-bucket edge capacity; avg 1024, max ~1300 << 2048

typedef _Float16 half2v __attribute__((ext_vector_type(2)));
typedef _Float16 half4v __attribute__((ext_vector_type(4)));
typedef _Float16 half8v __attribute__((ext_vector_type(8)));
typedef __attribute__((ext_vector_type(4))) float f32x4;

__device__ inline float fdot2h(half2v a, half2v b, float c) {
#if __has_builtin(__builtin_amdgcn_fdot2)
  return __builtin_amdgcn_fdot2(a, b, c, false);
#else
  return fmaf((float)a.x, (float)b.x, fmaf((float)a.y, (float)b.y, c));
#endif
}

__device__ inline half2v h2cast(unsigned u) { return __builtin_bit_cast(half2v, u); }

// ---------------- prep: W -> f16 FRAGMENT-MAJOR + zero bucket cursors --------
__global__ __launch_bounds__(256) void prep_kernel(
    const float* __restrict__ Wq, const float* __restrict__ Wk,
    const float* __restrict__ Wv, _Float16* __restrict__ wtf,
    int* __restrict__ gcur, int nbuck) {
  int tid = blockIdx.x * 256 + threadIdx.x;
  if (tid < 3 * NDIM * NDIM) {
    int mat = tid >> 14;
    int rem = tid & 16383;
    int mtg = rem >> 11;
    int kk = (rem >> 9) & 3;
    int lane = (rem >> 3) & 63;
    int j = rem & 7;
    int m = mtg * 16 + (lane & 15);
    int kx = kk * 32 + (lane >> 4) * 8 + j;
    const float* W = (mat == 0) ? Wq : (mat == 1) ? Wk : Wv;
    wtf[tid] = (_Float16)W[kx * NDIM + m];
  }
  int nthr = gridDim.x * 256;
  int tot = nbuck * 16;
  for (int i = tid; i < tot; i += nthr) gcur[i] = 0;
}

// ------------- fused heterogeneous kernel: partitionA-blocks + qkv-blocks ----
// blockIdx < nscat: coarse radix partition by dst>>6, 8 edges/thread; pairs
//   stored COMPRESSED as u32 = src<<6 | (dst&63)  (src < 50000 < 2^16).
// blockIdx >= nscat: f16 MFMA projections; wave = 16 rows x 128 cols;
//   k,v written INTERLEAVED in kvh.
__global__ __launch_bounds__(512) void fused_kernel(
    const float* __restrict__ z, const _Float16* __restrict__ wtf,
    const float* __restrict__ bq, const float* __restrict__ bk,
    const float* __restrict__ bv,
    _Float16* __restrict__ qh, _Float16* __restrict__ kvh,
    int n,
    const int* __restrict__ src, const int* __restrict__ dst,
    int* __restrict__ gcur, unsigned* __restrict__ part, int ne, int nbuck,
    int nscat) {
  __shared__ int lhist[1024];
  __shared__ int lbase[1024];
  __shared__ int lcur[1024];
  if ((int)blockIdx.x < nscat) {
    // ---- partition-A role: 8 edges per thread, two LDS passes ----
    int tid = threadIdx.x;
    for (int i = tid; i < nbuck; i += 512) lhist[i] = 0;
    __syncthreads();
    int e0 = (blockIdx.x * 512 + tid) * 8;
    int dd[8], ss[8];
    bool vv[8];
    if (e0 + 7 < ne) {
      int4 d0 = *(const int4*)(dst + e0);
      int4 d1 = *(const int4*)(dst + e0 + 4);
      int4 s0 = *(const int4*)(src + e0);
      int4 s1 = *(const int4*)(src + e0 + 4);
      dd[0] = d0.x; dd[1] = d0.y; dd[2] = d0.z; dd[3] = d0.w;
      dd[4] = d1.x; dd[5] = d1.y; dd[6] = d1.z; dd[7] = d1.w;
      ss[0] = s0.x; ss[1] = s0.y; ss[2] = s0.z; ss[3] = s0.w;
      ss[4] = s1.x; ss[5] = s1.y; ss[6] = s1.z; ss[7] = s1.w;
#pragma unroll
      for (int i = 0; i < 8; ++i) vv[i] = true;
    } else {
#pragma unroll
      for (int i = 0; i < 8; ++i) {
        vv[i] = (e0 + i) < ne;
        dd[i] = vv[i] ? dst[e0 + i] : 0;
        ss[i] = vv[i] ? src[e0 + i] : 0;
      }
    }
#pragma unroll
    for (int i = 0; i < 8; ++i)
      if (vv[i]) atomicAdd(&lhist[dd[i] >> 6], 1);
    __syncthreads();
    for (int b = tid; b < nbuck; b += 512) {
      int c = lhist[b];
      lbase[b] = (c > 0) ? atomicAdd(&gcur[b * 16], c) : 0;
      lcur[b] = 0;
    }
    __syncthreads();
#pragma unroll
    for (int i = 0; i < 8; ++i) {
      if (vv[i]) {
        int b = dd[i] >> 6;
        int p = lbase[b] + atomicAdd(&lcur[b], 1);
        if (p < BCAP)
          part[(size_t)b * BCAP + p] =
              ((unsigned)ss[i] << 6) | (unsigned)(dd[i] & 63);
      }
    }
    return;
  }
  // ---- qkv role: 8 waves; wave = 16 rows x 128 cols ----
  int bid = blockIdx.x - nscat;
  int lane = threadIdx.x & 63;
  int w = threadIdx.x >> 6;
  int l15 = lane & 15, kgrp = lane >> 4;
  int row_b = bid * 128 + w * 16 + l15;
  bool ok = row_b < n;
  const float* zrow = z + (size_t)row_b * NDIM;
  half8v bfr[4];
#pragma unroll
  for (int kk = 0; kk < 4; ++kk) {
    half8v bv8 = (half8v)0;
    if (ok) {
      const float4* zp = (const float4*)(zrow + kk * 32 + kgrp * 8);
      float4 a0 = zp[0], a1 = zp[1];
      bv8[0] = (_Float16)a0.x; bv8[1] = (_Float16)a0.y;
      bv8[2] = (_Float16)a0.z; bv8[3] = (_Float16)a0.w;
      bv8[4] = (_Float16)a1.x; bv8[5] = (_Float16)a1.y;
      bv8[6] = (_Float16)a1.z; bv8[7] = (_Float16)a1.w;
    }
    bfr[kk] = bv8;
  }
#pragma unroll
  for (int mat = 0; mat < 3; ++mat) {
    const _Float16* wf = wtf + (size_t)mat * NDIM * NDIM;
    const float* bias = (mat == 0) ? bq : (mat == 1) ? bk : bv;
    _Float16* outp = (mat == 0) ? qh : kvh;
    int rstride = (mat == 0) ? NDIM : 2 * NDIM;
    int coff = (mat == 2) ? NDIM : 0;
    f32x4 acc[8];
#pragma unroll
    for (int mtg = 0; mtg < 8; ++mtg) acc[mtg] = (f32x4)0.f;
#pragma unroll
    for (int mtg = 0; mtg < 8; ++mtg) {
#pragma unroll
      for (int kk = 0; kk < 4; ++kk) {
        half8v afr = *(const half8v*)(wf + (((mtg * 4 + kk) * 64) + lane) * 8);
        acc[mtg] = __builtin_amdgcn_mfma_f32_16x16x32_f16(afr, bfr[kk], acc[mtg],
                                                          0, 0, 0);
      }
    }
    if (ok) {
#pragma unroll
      for (int mtg = 0; mtg < 8; ++mtg) {
        int c0 = mtg * 16 + kgrp * 4;
        float4 bb = *(const float4*)(bias + c0);
        half4v pk;
        pk[0] = (_Float16)(acc[mtg][0] + bb.x);
        pk[1] = (_Float16)(acc[mtg][1] + bb.y);
        pk[2] = (_Float16)(acc[mtg][2] + bb.z);
        pk[3] = (_Float16)(acc[mtg][3] + bb.w);
        *(half4v*)(outp + (size_t)row_b * rstride + coff + c0) = pk;
      }
    }
  }
}

// ---------------- mega-agg: per-bucket LDS rank + softmax-aggregate ----------
// Block = bucket of 64 nodes, 512 threads (8 waves) -> 782 blocks = 3.05/CU
// (even load). Phase 1: rank bucket's u32 pairs into LDS u16 slot lists.
// Phase 2: each wave aggregates 8 nodes with the 4-group pipeline; k,v
// gathered from interleaved kvh rows. Static-max softmax (exp(e-8)).
__global__ __launch_bounds__(512) void megaagg_kernel(
    const _Float16* __restrict__ qh, const _Float16* __restrict__ kvh,
    const unsigned* __restrict__ part, const int* __restrict__ gcur,
    float* __restrict__ out, int n) {
  __shared__ unsigned short lslots[64 * CAP];  // 8 KB
  __shared__ int lcur[64];
  int tid = threadIdx.x;
  int nb = blockIdx.x;
  if (tid < 64) lcur[tid] = 0;
  __syncthreads();
  int cnt = gcur[nb * 16];
  if (cnt > BCAP) cnt = BCAP;
  const unsigned* pp = part + (size_t)nb * BCAP;
  for (int i = tid; i < cnt; i += 512) {
    unsigned p = pp[i];
    int nl = (int)(p & 63u);
    int r = atomicAdd(&lcur[nl], 1);
    if (r < CAP) lslots[(nl << 6) + r] = (unsigned short)(p >> 6);
  }
  __syncthreads();
  const float tau = 0.08838834764831845f;  // 1/sqrt(128)
  const float M0 = 8.0f;                   // static max guard
  int wv = tid >> 6;
  int lane = tid & 63;
  int gl = lane & 15;   // lane in group: dims [gl*8, gl*8+8)
  int grp = lane >> 4;  // group 0..3
#pragma unroll
  for (int t = 0; t < 8; ++t) {
    int nl = wv * 8 + t;
    int node = nb * 64 + nl;
    if (node >= n) break;  // wave-uniform
    int cnt2 = lcur[nl];
    if (cnt2 > CAP) cnt2 = CAP;
    uint4 qv = *(const uint4*)(qh + (size_t)node * NDIM + gl * 8);
    half2v q0 = h2cast(qv.x), q1 = h2cast(qv.y);
    half2v q2 = h2cast(qv.z), q3 = h2cast(qv.w);
    float se = 0.f;
    float h[8];
#pragma unroll
    for (int i = 0; i < 8; ++i) h[i] = 0.f;
    int sj = (lane < cnt2) ? (int)lslots[(nl << 6) + lane] : 0;
    int nsub = (cnt2 + 3) >> 2;
    for (int s = 0; s < nsub; ++s) {
      int j = (s << 2) | grp;
      int row = __shfl(sj, j);
      bool en = j < cnt2;  // uniform within a 16-lane group
      uint4 kv, vv;
      if (en) {  // k and v in ONE 512B row -> locality + 2 loads in flight
        const _Float16* kvrow = kvh + (size_t)row * 2 * NDIM;
        kv = *(const uint4*)(kvrow + gl * 8);
        vv = *(const uint4*)(kvrow + NDIM + gl * 8);
      }
      if (en) {
        float p = fdot2h(h2cast(kv.x), q0, 0.f);
        p = fdot2h(h2cast(kv.y), q1, p);
        p = fdot2h(h2cast(kv.z), q2, p);
        p = fdot2h(h2cast(kv.w), q3, p);
        p += __shfl_xor(p, 1);
        p += __shfl_xor(p, 2);
        p += __shfl_xor(p, 4);
        p += __shfl_xor(p, 8);
        float ex = __expf(fmaf(p, tau, -M0));
        se += ex;
        half2v v0 = h2cast(vv.x), v1 = h2cast(vv.y);
        half2v v2 = h2cast(vv.z), v3 = h2cast(vv.w);
        h[0] = fmaf(ex, (float)v0.x, h[0]);
        h[1] = fmaf(ex, (float)v0.y, h[1]);
        h[2] = fmaf(ex, (float)v1.x, h[2]);
        h[3] = fmaf(ex, (float)v1.y, h[3]);
        h[4] = fmaf(ex, (float)v2.x, h[4]);
        h[5] = fmaf(ex, (float)v2.y, h[5]);
        h[6] = fmaf(ex, (float)v3.x, h[6]);
        h[7] = fmaf(ex, (float)v3.y, h[7]);
      }
    }
    // cross-group reduce (se uniform within group; h partial per group)
    se += __shfl_xor(se, 16);
    se += __shfl_xor(se, 32);
#pragma unroll
    for (int i = 0; i < 8; ++i) {
      h[i] += __shfl_xor(h[i], 16);
      h[i] += __shfl_xor(h[i], 32);
    }
    if (grp == 0) {
      float inv = 1.f / ((se > 0.f) ? se : 1.f);
      float4* op = (float4*)(out + (size_t)node * NDIM + gl * 8);
      op[0] = make_float4(h[0] * inv, h[1] * inv, h[2] * inv, h[3] * inv);
      op[1] = make_float4(h[4] * inv, h[5] * inv, h[6] * inv, h[7] * inv);
    }
  }
}

extern "C" void kernel_launch(void* const* d_in, const int* in_sizes, int n_in,
                              void* d_out, int out_size, void* d_ws, size_t ws_size,
                              hipStream_t stream) {
  const float* z  = (const float*)d_in[0];
  const float* Wq = (const float*)d_in[1];
  const float* bq = (const float*)d_in[2];
  const float* Wk = (const float*)d_in[3];
  const float* bk = (const float*)d_in[4];
  const float* Wv = (const float*)d_in[5];
  const float* bv = (const float*)d_in[6];
  const int* src  = (const int*)d_in[7];
  const int* dst  = (const int*)d_in[8];
  int n  = in_sizes[0] / NDIM;  // 50000
  int ne = in_sizes[7];         // 800000
  float* out = (float*)d_out;

  int nbuck = (n + 63) >> 6;  // 782 buckets of 64 nodes (dst>>6); <=1024

  char* ws = (char*)d_ws;
  size_t szh = (size_t)n * NDIM * sizeof(_Float16);  // 12.8 MB
  size_t off = 0;
  _Float16* qh  = (_Float16*)(ws + off); off += szh;
  _Float16* kvh = (_Float16*)(ws + off); off += 2 * szh;  // interleaved k|v
  _Float16* wtf = (_Float16*)(ws + off);
  off += ((size_t)3 * NDIM * NDIM * sizeof(_Float16) + 255) & ~(size_t)255;
  int* gcur = (int*)(ws + off);
  off += (((size_t)nbuck * 16 * sizeof(int)) + 255) & ~(size_t)255;  // 50 KB
  unsigned* part = (unsigned*)(ws + off);
  off += (size_t)nbuck * BCAP * sizeof(unsigned);                    // 6.4 MB

  int nscat = (ne / 8 + 511) / 512;  // 196 partition-A blocks (8 edges/thread)
  int nqkv  = (n + 127) / 128;       // 391 qkv blocks (128 rows each)

  // 1) W -> f16 fragment-major, zero bucket cursors
  prep_kernel<<<256, 256, 0, stream>>>(Wq, Wk, Wv, wtf, gcur, nbuck);
  // 2) fused: partition-A blocks (first) + qkv-MFMA-blocks (kv interleaved)
  fused_kernel<<<nscat + nqkv, 512, 0, stream>>>(z, wtf, bq, bk, bv, qh, kvh, n,
                                                 src, dst, gcur, part, ne, nbuck,
                                                 nscat);
  // 3) mega-agg: per-bucket LDS rank + softmax-aggregate (64-node buckets)
  megaagg_kernel<<<nbuck, 512, 0, stream>>>(qh, kvh, part, gcur, out, n);
}

// Round 16
// 110.074 us; speedup vs baseline: 1.0871x; 1.0577x over previous
//
#include <hip/hip_runtime.h>
#include <math.h>

#define NDIM 128
#define CAP 64     // per-node slot capacity; deg ~ Poisson(16), max ~40 << 64
#define BCAP 4096  // per-bucket edge capacity; avg 2046, max ~2350 << 4096

typedef _Float16 half2v __attribute__((ext_vector_type(2)));
typedef _Float16 half4v __attribute__((ext_vector_type(4)));
typedef _Float16 half8v __attribute__((ext_vector_type(8)));
typedef __attribute__((ext_vector_type(4))) float f32x4;

__device__ inline float fdot2h(half2v a, half2v b, float c) {
#if __has_builtin(__builtin_amdgcn_fdot2)
  return __builtin_amdgcn_fdot2(a, b, c, false);
#else
  return fmaf((float)a.x, (float)b.x, fmaf((float)a.y, (float)b.y, c));
#endif
}

__device__ inline half2v h2cast(unsigned u) { return __builtin_bit_cast(half2v, u); }

// ---------------- prep: W -> f16 FRAGMENT-MAJOR + zero bucket cursors --------
__global__ __launch_bounds__(256) void prep_kernel(
    const float* __restrict__ Wq, const float* __restrict__ Wk,
    const float* __restrict__ Wv, _Float16* __restrict__ wtf,
    int* __restrict__ gcur, int nbuck) {
  int tid = blockIdx.x * 256 + threadIdx.x;
  if (tid < 3 * NDIM * NDIM) {
    int mat = tid >> 14;
    int rem = tid & 16383;
    int mtg = rem >> 11;
    int kk = (rem >> 9) & 3;
    int lane = (rem >> 3) & 63;
    int j = rem & 7;
    int m = mtg * 16 + (lane & 15);
    int kx = kk * 32 + (lane >> 4) * 8 + j;
    const float* W = (mat == 0) ? Wq : (mat == 1) ? Wk : Wv;
    wtf[tid] = (_Float16)W[kx * NDIM + m];
  }
  int nthr = gridDim.x * 256;
  int tot = nbuck * 16;
  for (int i = tid; i < tot; i += nthr) gcur[i] = 0;
}

// ------------- fused heterogeneous kernel: partitionA-blocks + qkv-blocks ----
// blockIdx < nscat: coarse radix partition by dst>>7, 8 edges/thread; pairs
//   stored COMPRESSED as u32 = src<<7 | (dst&127)  (src < 50000 < 2^16).
// blockIdx >= nscat: f16 MFMA projections; wave = 16 rows x 128 cols;
//   k,v written INTERLEAVED in kvh.
__global__ __launch_bounds__(512) void fused_kernel(
    const float* __restrict__ z, const _Float16* __restrict__ wtf,
    const float* __restrict__ bq, const float* __restrict__ bk,
    const float* __restrict__ bv,
    _Float16* __restrict__ qh, _Float16* __restrict__ kvh,
    int n,
    const int* __restrict__ src, const int* __restrict__ dst,
    int* __restrict__ gcur, unsigned* __restrict__ part, int ne, int nbuck,
    int nscat) {
  __shared__ int lhist[512];
  __shared__ int lbase[512];
  __shared__ int lcur[512];
  if ((int)blockIdx.x < nscat) {
    // ---- partition-A role: 8 edges per thread, two LDS passes ----
    int tid = threadIdx.x;
    for (int i = tid; i < nbuck; i += 512) lhist[i] = 0;
    __syncthreads();
    int e0 = (blockIdx.x * 512 + tid) * 8;
    int dd[8], ss[8];
    bool vv[8];
    if (e0 + 7 < ne) {
      int4 d0 = *(const int4*)(dst + e0);
      int4 d1 = *(const int4*)(dst + e0 + 4);
      int4 s0 = *(const int4*)(src + e0);
      int4 s1 = *(const int4*)(src + e0 + 4);
      dd[0] = d0.x; dd[1] = d0.y; dd[2] = d0.z; dd[3] = d0.w;
      dd[4] = d1.x; dd[5] = d1.y; dd[6] = d1.z; dd[7] = d1.w;
      ss[0] = s0.x; ss[1] = s0.y; ss[2] = s0.z; ss[3] = s0.w;
      ss[4] = s1.x; ss[5] = s1.y; ss[6] = s1.z; ss[7] = s1.w;
#pragma unroll
      for (int i = 0; i < 8; ++i) vv[i] = true;
    } else {
#pragma unroll
      for (int i = 0; i < 8; ++i) {
        vv[i] = (e0 + i) < ne;
        dd[i] = vv[i] ? dst[e0 + i] : 0;
        ss[i] = vv[i] ? src[e0 + i] : 0;
      }
    }
#pragma unroll
    for (int i = 0; i < 8; ++i)
      if (vv[i]) atomicAdd(&lhist[dd[i] >> 7], 1);
    __syncthreads();
    for (int b = tid; b < nbuck; b += 512) {
      int c = lhist[b];
      lbase[b] = (c > 0) ? atomicAdd(&gcur[b * 16], c) : 0;
      lcur[b] = 0;
    }
    __syncthreads();
#pragma unroll
    for (int i = 0; i < 8; ++i) {
      if (vv[i]) {
        int b = dd[i] >> 7;
        int p = lbase[b] + atomicAdd(&lcur[b], 1);
        if (p < BCAP)
          part[(size_t)b * BCAP + p] =
              ((unsigned)ss[i] << 7) | (unsigned)(dd[i] & 127);
      }
    }
    return;
  }
  // ---- qkv role: 8 waves; wave = 16 rows x 128 cols ----
  int bid = blockIdx.x - nscat;
  int lane = threadIdx.x & 63;
  int w = threadIdx.x >> 6;
  int l15 = lane & 15, kgrp = lane >> 4;
  int row_b = bid * 128 + w * 16 + l15;
  bool ok = row_b < n;
  const float* zrow = z + (size_t)row_b * NDIM;
  half8v bfr[4];
#pragma unroll
  for (int kk = 0; kk < 4; ++kk) {
    half8v bv8 = (half8v)0;
    if (ok) {
      const float4* zp = (const float4*)(zrow + kk * 32 + kgrp * 8);
      float4 a0 = zp[0], a1 = zp[1];
      bv8[0] = (_Float16)a0.x; bv8[1] = (_Float16)a0.y;
      bv8[2] = (_Float16)a0.z; bv8[3] = (_Float16)a0.w;
      bv8[4] = (_Float16)a1.x; bv8[5] = (_Float16)a1.y;
      bv8[6] = (_Float16)a1.z; bv8[7] = (_Float16)a1.w;
    }
    bfr[kk] = bv8;
  }
#pragma unroll
  for (int mat = 0; mat < 3; ++mat) {
    const _Float16* wf = wtf + (size_t)mat * NDIM * NDIM;
    const float* bias = (mat == 0) ? bq : (mat == 1) ? bk : bv;
    _Float16* outp = (mat == 0) ? qh : kvh;
    int rstride = (mat == 0) ? NDIM : 2 * NDIM;
    int coff = (mat == 2) ? NDIM : 0;
    f32x4 acc[8];
#pragma unroll
    for (int mtg = 0; mtg < 8; ++mtg) acc[mtg] = (f32x4)0.f;
#pragma unroll
    for (int mtg = 0; mtg < 8; ++mtg) {
#pragma unroll
      for (int kk = 0; kk < 4; ++kk) {
        half8v afr = *(const half8v*)(wf + (((mtg * 4 + kk) * 64) + lane) * 8);
        acc[mtg] = __builtin_amdgcn_mfma_f32_16x16x32_f16(afr, bfr[kk], acc[mtg],
                                                          0, 0, 0);
      }
    }
    if (ok) {
#pragma unroll
      for (int mtg = 0; mtg < 8; ++mtg) {
        int c0 = mtg * 16 + kgrp * 4;
        float4 bb = *(const float4*)(bias + c0);
        half4v pk;
        pk[0] = (_Float16)(acc[mtg][0] + bb.x);
        pk[1] = (_Float16)(acc[mtg][1] + bb.y);
        pk[2] = (_Float16)(acc[mtg][2] + bb.z);
        pk[3] = (_Float16)(acc[mtg][3] + bb.w);
        *(half4v*)(outp + (size_t)row_b * rstride + coff + c0) = pk;
      }
    }
  }
}

// ---------------- mega-agg: per-bucket LDS rank + softmax-aggregate ----------
// Block = bucket of 128 nodes, 1024 threads (16 waves) — round-14 geometry
// (measured best: 64.7 vs 67.1 for 64-node buckets). Phase 1: rank bucket's
// u32 pairs into LDS u16 slot lists. Phase 2: each wave aggregates 8 nodes
// with the 4-group pipeline; k,v gathered from interleaved kvh rows.
// Static-max softmax (exp(e-8), identical ratio).
__global__ __launch_bounds__(1024) void megaagg_kernel(
    const _Float16* __restrict__ qh, const _Float16* __restrict__ kvh,
    const unsigned* __restrict__ part, const int* __restrict__ gcur,
    float* __restrict__ out, int n) {
  __shared__ unsigned short lslots[128 * CAP];  // 16 KB
  __shared__ int lcur[128];
  int tid = threadIdx.x;
  int nb = blockIdx.x;
  if (tid < 128) lcur[tid] = 0;
  __syncthreads();
  int cnt = gcur[nb * 16];
  if (cnt > BCAP) cnt = BCAP;
  const unsigned* pp = part + (size_t)nb * BCAP;
  for (int i = tid; i < cnt; i += 1024) {
    unsigned p = pp[i];
    int nl = (int)(p & 127u);
    int r = atomicAdd(&lcur[nl], 1);
    if (r < CAP) lslots[(nl << 6) + r] = (unsigned short)(p >> 7);
  }
  __syncthreads();
  const float tau = 0.08838834764831845f;  // 1/sqrt(128)
  const float M0 = 8.0f;                   // static max guard
  int wv = tid >> 6;
  int lane = tid & 63;
  int gl = lane & 15;   // lane in group: dims [gl*8, gl*8+8)
  int grp = lane >> 4;  // group 0..3
#pragma unroll
  for (int t = 0; t < 8; ++t) {
    int nl = wv * 8 + t;
    int node = nb * 128 + nl;
    if (node >= n) break;  // wave-uniform
    int cnt2 = lcur[nl];
    if (cnt2 > CAP) cnt2 = CAP;
    uint4 qv = *(const uint4*)(qh + (size_t)node * NDIM + gl * 8);
    half2v q0 = h2cast(qv.x), q1 = h2cast(qv.y);
    half2v q2 = h2cast(qv.z), q3 = h2cast(qv.w);
    float se = 0.f;
    float h[8];
#pragma unroll
    for (int i = 0; i < 8; ++i) h[i] = 0.f;
    int sj = (lane < cnt2) ? (int)lslots[(nl << 6) + lane] : 0;
    int nsub = (cnt2 + 3) >> 2;
    for (int s = 0; s < nsub; ++s) {
      int j = (s << 2) | grp;
      int row = __shfl(sj, j);
      bool en = j < cnt2;  // uniform within a 16-lane group
      uint4 kv, vv;
      if (en) {  // k and v in ONE 512B row -> locality + 2 loads in flight
        const _Float16* kvrow = kvh + (size_t)row * 2 * NDIM;
        kv = *(const uint4*)(kvrow + gl * 8);
        vv = *(const uint4*)(kvrow + NDIM + gl * 8);
      }
      if (en) {
        float p = fdot2h(h2cast(kv.x), q0, 0.f);
        p = fdot2h(h2cast(kv.y), q1, p);
        p = fdot2h(h2cast(kv.z), q2, p);
        p = fdot2h(h2cast(kv.w), q3, p);
        p += __shfl_xor(p, 1);
        p += __shfl_xor(p, 2);
        p += __shfl_xor(p, 4);
        p += __shfl_xor(p, 8);
        float ex = __expf(fmaf(p, tau, -M0));
        se += ex;
        half2v v0 = h2cast(vv.x), v1 = h2cast(vv.y);
        half2v v2 = h2cast(vv.z), v3 = h2cast(vv.w);
        h[0] = fmaf(ex, (float)v0.x, h[0]);
        h[1] = fmaf(ex, (float)v0.y, h[1]);
        h[2] = fmaf(ex, (float)v1.x, h[2]);
        h[3] = fmaf(ex, (float)v1.y, h[3]);
        h[4] = fmaf(ex, (float)v2.x, h[4]);
        h[5] = fmaf(ex, (float)v2.y, h[5]);
        h[6] = fmaf(ex, (float)v3.x, h[6]);
        h[7] = fmaf(ex, (float)v3.y, h[7]);
      }
    }
    // cross-group reduce (se uniform within group; h partial per group)
    se += __shfl_xor(se, 16);
    se += __shfl_xor(se, 32);
#pragma unroll
    for (int i = 0; i < 8; ++i) {
      h[i] += __shfl_xor(h[i], 16);
      h[i] += __shfl_xor(h[i], 32);
    }
    if (grp == 0) {
      float inv = 1.f / ((se > 0.f) ? se : 1.f);
      float4* op = (float4*)(out + (size_t)node * NDIM + gl * 8);
      op[0] = make_float4(h[0] * inv, h[1] * inv, h[2] * inv, h[3] * inv);
      op[1] = make_float4(h[4] * inv, h[5] * inv, h[6] * inv, h[7] * inv);
    }
  }
}

extern "C" void kernel_launch(void* const* d_in, const int* in_sizes, int n_in,
                              void* d_out, int out_size, void* d_ws, size_t ws_size,
                              hipStream_t stream) {
  const float* z  = (const float*)d_in[0];
  const float* Wq = (const float*)d_in[1];
  const float* bq = (const float*)d_in[2];
  const float* Wk = (const float*)d_in[3];
  const float* bk = (const float*)d_in[4];
  const float* Wv = (const float*)d_in[5];
  const float* bv = (const float*)d_in[6];
  const int* src  = (const int*)d_in[7];
  const int* dst  = (const int*)d_in[8];
  int n  = in_sizes[0] / NDIM;  // 50000
  int ne = in_sizes[7];         // 800000
  float* out = (float*)d_out;

  int nbuck = (n + 127) >> 7;  // 391 buckets of 128 nodes (dst>>7); <=512

  char* ws = (char*)d_ws;
  size_t szh = (size_t)n * NDIM * sizeof(_Float16);  // 12.8 MB
  size_t off = 0;
  _Float16* qh  = (_Float16*)(ws + off); off += szh;
  _Float16* kvh = (_Float16*)(ws + off); off += 2 * szh;  // interleaved k|v
  _Float16* wtf = (_Float16*)(ws + off);
  off += ((size_t)3 * NDIM * NDIM * sizeof(_Float16) + 255) & ~(size_t)255;
  int* gcur = (int*)(ws + off);
  off += (((size_t)nbuck * 16 * sizeof(int)) + 255) & ~(size_t)255;  // 25 KB
  unsigned* part = (unsigned*)(ws + off);
  off += (size_t)nbuck * BCAP * sizeof(unsigned);                    // 6.4 MB

  int nscat = (ne / 8 + 511) / 512;  // 196 partition-A blocks (8 edges/thread)
  int nqkv  = (n + 127) / 128;       // 391 qkv blocks (128 rows each)

  // 1) W -> f16 fragment-major, zero bucket cursors
  prep_kernel<<<256, 256, 0, stream>>>(Wq, Wk, Wv, wtf, gcur, nbuck);
  // 2) fused: partition-A blocks (first) + qkv-MFMA-blocks (kv interleaved)
  fused_kernel<<<nscat + nqkv, 512, 0, stream>>>(z, wtf, bq, bk, bv, qh, kvh, n,
                                                 src, dst, gcur, part, ne, nbuck,
                                                 nscat);
  // 3) mega-agg: per-bucket LDS rank + softmax-aggregate (128-node buckets)
  megaagg_kernel<<<nbuck, 1024, 0, stream>>>(qh, kvh, part, gcur, out, n);
}